// Round 5
// baseline (173.629 us; speedup 1.0000x reference)
//
#include <hip/hip_runtime.h>
#include <math.h>

#define D_DIM   1024
#define BS      80      // B * STEP
#define STEPS   5
#define ALPHA   0.01f
#define BN_EPS  1e-5f
#define L2_EPS  1e-12f

#define NG      8       // n-groups
#define NROWS   10      // rows per n-group (NG*NROWS == BS)
#define JBLK    128     // j-blocks of 8 columns each
#define G_BLOCKS (NG * JBLK)   // 1024 blocks; exactly 4 blocks/CU

#define NCTR       64   // distributed completion counters
#define CTR_STRIDE 32   // ints between counters (128 B -> no line sharing)
#define BLK_PER_CTR (G_BLOCKS / NCTR)   // 16

// ---------------------------------------------------------------------------
// kQ: closed-form fast-weight readout, one block per row (computed ONCE).
//   q[n,i] = ALPHA * sum_{s<=t} c_s x_k[s][i] prod_{r=s+1..t}(1-ALPHA x_k[r][i]^2)
//   t = n>>4, bb = n&15; keys x[bb*5+s], query v = x[n], c_s = dot(key_s, v).
// Block 0 also zeroes the 64 completion counters for kG (workspace is
// poisoned by the harness every iteration, so this must be done on-device).
// ---------------------------------------------------------------------------
__global__ __launch_bounds__(256) void kQ(const float* __restrict__ x,
                                          float* __restrict__ q,
                                          int* __restrict__ ctr) {
    const int n    = blockIdx.x;
    const int tid  = threadIdx.x;
    const int lane = tid & 63;
    const int wid  = tid >> 6;
    const int t    = n >> 4;
    const int bb   = n & 15;

    if (n == 0 && tid < NCTR) ctr[tid * CTR_STRIDE] = 0;

    const float4* __restrict__ xv = (const float4*)(x + (size_t)n * D_DIM);
    const float4 v = xv[tid];

    float4 k[STEPS];
#pragma unroll
    for (int s = 0; s < STEPS; ++s)
        k[s] = ((const float4*)(x + (size_t)(bb * STEPS + s) * D_DIM))[tid];

    float p[STEPS];
#pragma unroll
    for (int s = 0; s < STEPS; ++s)
        p[s] = k[s].x * v.x + k[s].y * v.y + k[s].z * v.z + k[s].w * v.w;

#pragma unroll
    for (int off = 32; off; off >>= 1) {
#pragma unroll
        for (int s = 0; s < STEPS; ++s) p[s] += __shfl_xor(p[s], off, 64);
    }

    __shared__ float sh[4][STEPS];
    if (lane == 0) {
#pragma unroll
        for (int s = 0; s < STEPS; ++s) sh[wid][s] = p[s];
    }
    __syncthreads();
    float c[STEPS];
#pragma unroll
    for (int s = 0; s < STEPS; ++s)
        c[s] = sh[0][s] + sh[1][s] + sh[2][s] + sh[3][s];

    float4 acc = make_float4(0.f, 0.f, 0.f, 0.f);
    for (int s = 0; s <= t; ++s) {
        const float4 xs = k[s];
        acc.x = acc.x * (1.f - ALPHA * xs.x * xs.x) + c[s] * xs.x;
        acc.y = acc.y * (1.f - ALPHA * xs.y * xs.y) + c[s] * xs.y;
        acc.z = acc.z * (1.f - ALPHA * xs.z * xs.z) + c[s] * xs.z;
        acc.w = acc.w * (1.f - ALPHA * xs.w * xs.w) + c[s] * xs.w;
    }
    acc.x *= ALPHA; acc.y *= ALPHA; acc.z *= ALPHA; acc.w *= ALPHA;
    ((float4*)(q + (size_t)n * D_DIM))[tid] = acc;
}

// ---------------------------------------------------------------------------
// kG: y = q @ W^T + b, per-(ng,j) partial BN stats, then fused BN+ReLU+L2
// finisher (kB's work) done by blocks 0..79 after a distributed-counter
// completion barrier.
//
//   bid = ng*128 + jb. Blocks sharing jb (same 8 W rows) are ≡ mod 8 ->
//   same XCD under round-robin dispatch -> W row fetched from HBM once.
//   Per block: 8 j x 10 n; wave wid owns j = j0+2*wid,+1 (2 W rows = 32
//   VGPRs); q tile staged into 40 KiB LDS. 4 blocks/CU -> ALL 1024 blocks
//   co-resident (finisher spin is deadlock-free even if they weren't:
//   finishers are the first-dispatched bids).
//
//   Completion protocol (round-1 lesson: ONE contended counter-line
//   serializes ~1024 RMWs -> ~200 us; distribute over 64 lines, 16 deep):
//   each block: __threadfence (release own y/psum stores) -> syncthreads ->
//   tid0 atomicAdd(ctr[bid>>4], release). Finisher block n<80: lanes 0..63
//   of wave 0 each spin-poll one counter (acquire, s_sleep backoff) until
//   it reaches 16; syncthreads; threadfence (acquire-side invalidate);
//   then BN+ReLU+L2norm for row n.
// ---------------------------------------------------------------------------
__global__ __launch_bounds__(256, 4) void kG(const float* __restrict__ q,
                                             const float* __restrict__ W,
                                             const float* __restrict__ bvec,
                                             float* __restrict__ y,
                                             float* __restrict__ psum,
                                             float* __restrict__ psq,
                                             int* __restrict__ ctr,
                                             const float* __restrict__ gamma,
                                             const float* __restrict__ beta,
                                             float* __restrict__ out) {
    const int tid  = threadIdx.x;
    const int lane = tid & 63;
    const int wid  = tid >> 6;
    const int bid  = blockIdx.x;
    const int ng   = bid >> 7;         // 0..7
    const int jb   = bid & 127;        // 0..127
    const int j0   = jb * 8;
    const int n0   = ng * NROWS;
    const int jw   = j0 + wid * 2;     // this wave's 2 columns

    __shared__ float qs[NROWS][D_DIM];  // 40 KiB

    // W fragment prefetch (in flight during q staging)
    const float4* __restrict__ W4 = (const float4*)W;
    float4 w[2][4];
#pragma unroll
    for (int jj = 0; jj < 2; ++jj)
#pragma unroll
        for (int m = 0; m < 4; ++m)
            w[jj][m] = W4[(size_t)(jw + jj) * 256 + lane + 64 * m];
    const float b0 = bvec[jw];
    const float b1 = bvec[jw + 1];

    // stage this n-group's q rows into LDS, fully coalesced
    {
        const float4* __restrict__ q4 = (const float4*)(q + (size_t)n0 * D_DIM);
        float4* __restrict__ qs4 = (float4*)qs;
#pragma unroll
        for (int i = 0; i < (NROWS * 256) / 256; ++i)
            qs4[tid + 256 * i] = q4[tid + 256 * i];
    }
    __syncthreads();

    float csum[2] = {0.f, 0.f};
    float csq [2] = {0.f, 0.f};

#pragma unroll 2
    for (int nn = 0; nn < NROWS; ++nn) {
        const int n = n0 + nn;
        float4 qv[4];
#pragma unroll
        for (int m = 0; m < 4; ++m)
            qv[m] = ((const float4*)qs[nn])[lane + 64 * m];

        float s0 = 0.f, s1 = 0.f;
#pragma unroll
        for (int m = 0; m < 4; ++m) {
            s0 += w[0][m].x * qv[m].x + w[0][m].y * qv[m].y
                + w[0][m].z * qv[m].z + w[0][m].w * qv[m].w;
            s1 += w[1][m].x * qv[m].x + w[1][m].y * qv[m].y
                + w[1][m].z * qv[m].z + w[1][m].w * qv[m].w;
        }
#pragma unroll
        for (int off = 32; off; off >>= 1) {
            s0 += __shfl_xor(s0, off, 64);
            s1 += __shfl_xor(s1, off, 64);
        }
        if (lane == 0) {
            const float y0 = s0 + b0;
            const float y1 = s1 + b1;
            ((float2*)(y + (size_t)n * D_DIM + jw))[0] = make_float2(y0, y1);
            csum[0] += y0; csum[1] += y1;
            csq [0] += y0 * y0; csq [1] += y1 * y1;
        }
    }
    if (lane == 0) {
        ((float2*)(psum + (size_t)ng * D_DIM + jw))[0] = make_float2(csum[0], csum[1]);
        ((float2*)(psq  + (size_t)ng * D_DIM + jw))[0] = make_float2(csq [0], csq [1]);
    }

    // ---- completion barrier (distributed) ----------------------------------
    __threadfence();                       // release this thread's stores
    __syncthreads();
    if (tid == 0)
        __hip_atomic_fetch_add(&ctr[(bid >> 4) * CTR_STRIDE], 1,
                               __ATOMIC_RELEASE, __HIP_MEMORY_SCOPE_AGENT);

    if (bid >= BS) return;                 // only blocks 0..79 finish

    if (wid == 0) {                        // lanes 0..63 each own one counter
        while (__hip_atomic_load(&ctr[lane * CTR_STRIDE],
                                 __ATOMIC_ACQUIRE, __HIP_MEMORY_SCOPE_AGENT)
               < BLK_PER_CTR)
            __builtin_amdgcn_s_sleep(16);
    }
    __syncthreads();
    __threadfence();                       // acquire-side: see released data

    // ---- finisher: BN + ReLU + row L2 normalize for row n = bid ------------
    {
        const int n = bid;

        float4 su = make_float4(0.f, 0.f, 0.f, 0.f);
        float4 sq = make_float4(0.f, 0.f, 0.f, 0.f);
#pragma unroll
        for (int g = 0; g < NG; ++g) {
            const float4 a = ((const float4*)psum)[g * 256 + tid];
            const float4 b = ((const float4*)psq )[g * 256 + tid];
            su.x += a.x; su.y += a.y; su.z += a.z; su.w += a.w;
            sq.x += b.x; sq.y += b.y; sq.z += b.z; sq.w += b.w;
        }
        const float inv_bs = 1.f / (float)BS;
        const float4 yv = ((const float4*)y)[(size_t)n * 256 + tid];
        const float4 g4 = ((const float4*)gamma)[tid];
        const float4 be = ((const float4*)beta)[tid];

        float4 o;
        {
            const float mu = su.x * inv_bs;
            const float istd = rsqrtf(sq.x * inv_bs - mu * mu + BN_EPS);
            o.x = fmaxf((yv.x - mu) * istd * g4.x + be.x, 0.f);
        }
        {
            const float mu = su.y * inv_bs;
            const float istd = rsqrtf(sq.y * inv_bs - mu * mu + BN_EPS);
            o.y = fmaxf((yv.y - mu) * istd * g4.y + be.y, 0.f);
        }
        {
            const float mu = su.z * inv_bs;
            const float istd = rsqrtf(sq.z * inv_bs - mu * mu + BN_EPS);
            o.z = fmaxf((yv.z - mu) * istd * g4.z + be.z, 0.f);
        }
        {
            const float mu = su.w * inv_bs;
            const float istd = rsqrtf(sq.w * inv_bs - mu * mu + BN_EPS);
            o.w = fmaxf((yv.w - mu) * istd * g4.w + be.w, 0.f);
        }

        float ss = o.x * o.x + o.y * o.y + o.z * o.z + o.w * o.w;
#pragma unroll
        for (int off = 32; off; off >>= 1) ss += __shfl_xor(ss, off, 64);
        __shared__ float sred[4];
        if (lane == 0) sred[wid] = ss;
        __syncthreads();
        const float stot = sred[0] + sred[1] + sred[2] + sred[3];

        const float scale = 1.f / fmaxf(sqrtf(stot), L2_EPS);
        float4 ov = make_float4(o.x * scale, o.y * scale, o.z * scale, o.w * scale);
        ((float4*)out)[(size_t)n * 256 + tid] = ov;
    }
}

extern "C" void kernel_launch(void* const* d_in, const int* in_sizes, int n_in,
                              void* d_out, int out_size, void* d_ws, size_t ws_size,
                              hipStream_t stream) {
    const float* x     = (const float*)d_in[0];
    const float* W     = (const float*)d_in[1];
    const float* bvec  = (const float*)d_in[2];
    const float* gamma = (const float*)d_in[3];
    const float* beta  = (const float*)d_in[4];

    float* q    = (float*)d_ws;          // 80*1024
    float* y    = q + BS * D_DIM;        // 80*1024
    float* psum = y + BS * D_DIM;        // 8*1024
    float* psq  = psum + NG * D_DIM;     // 8*1024
    int*   ctr  = (int*)(psq + NG * D_DIM); // 64*32 ints

    float* out = (float*)d_out;

    kQ<<<BS,       256, 0, stream>>>(x, q, ctr);
    kG<<<G_BLOCKS, 256, 0, stream>>>(q, W, bvec, y, psum, psq, ctr,
                                     gamma, beta, out);
}

// Round 6
// 78.655 us; speedup vs baseline: 2.2075x; 2.2075x over previous
//
#include <hip/hip_runtime.h>
#include <math.h>

#define D_DIM   1024
#define BS      80      // B * STEP
#define STEPS   5
#define ALPHA   0.01f
#define BN_EPS  1e-5f
#define L2_EPS  1e-12f

#define NGH     16      // n-half-groups
#define NROWS   5       // rows per half-group (NGH*NROWS == BS)
#define JBLK    64      // j-blocks of 16 columns each
#define G_BLOCKS (NGH * JBLK)  // 1024 blocks; 4 blocks/CU (VGPR-capped)

// ---------------------------------------------------------------------------
// kQ: closed-form fast-weight readout, one block per row (computed ONCE).
//   q[n,i] = ALPHA * sum_{s<=t} c_s x_k[s][i] prod_{r=s+1..t}(1-ALPHA x_k[r][i]^2)
//   t = n>>4, bb = n&15; keys x[bb*5+s], query v = x[n], c_s = dot(key_s, v).
// 256 threads x float4 = exact row fit.
// ---------------------------------------------------------------------------
__global__ __launch_bounds__(256) void kQ(const float* __restrict__ x,
                                          float* __restrict__ q) {
    const int n    = blockIdx.x;
    const int tid  = threadIdx.x;
    const int lane = tid & 63;
    const int wid  = tid >> 6;
    const int t    = n >> 4;
    const int bb   = n & 15;

    const float4* __restrict__ xv = (const float4*)(x + (size_t)n * D_DIM);
    const float4 v = xv[tid];

    float4 k[STEPS];
#pragma unroll
    for (int s = 0; s < STEPS; ++s)
        k[s] = ((const float4*)(x + (size_t)(bb * STEPS + s) * D_DIM))[tid];

    float p[STEPS];
#pragma unroll
    for (int s = 0; s < STEPS; ++s)
        p[s] = k[s].x * v.x + k[s].y * v.y + k[s].z * v.z + k[s].w * v.w;

#pragma unroll
    for (int off = 32; off; off >>= 1) {
#pragma unroll
        for (int s = 0; s < STEPS; ++s) p[s] += __shfl_xor(p[s], off, 64);
    }

    __shared__ float sh[4][STEPS];
    if (lane == 0) {
#pragma unroll
        for (int s = 0; s < STEPS; ++s) sh[wid][s] = p[s];
    }
    __syncthreads();
    float c[STEPS];
#pragma unroll
    for (int s = 0; s < STEPS; ++s)
        c[s] = sh[0][s] + sh[1][s] + sh[2][s] + sh[3][s];

    float4 acc = make_float4(0.f, 0.f, 0.f, 0.f);
    for (int s = 0; s <= t; ++s) {
        const float4 xs = k[s];
        acc.x = acc.x * (1.f - ALPHA * xs.x * xs.x) + c[s] * xs.x;
        acc.y = acc.y * (1.f - ALPHA * xs.y * xs.y) + c[s] * xs.y;
        acc.z = acc.z * (1.f - ALPHA * xs.z * xs.z) + c[s] * xs.z;
        acc.w = acc.w * (1.f - ALPHA * xs.w * xs.w) + c[s] * xs.w;
    }
    acc.x *= ALPHA; acc.y *= ALPHA; acc.z *= ALPHA; acc.w *= ALPHA;
    ((float4*)(q + (size_t)n * D_DIM))[tid] = acc;
}

// ---------------------------------------------------------------------------
// kG: y = q @ W^T + b with per-(ngh, j) partial BN stats. 1024 blocks.
//   bid = ngh*64 + jb.  Blocks sharing jb (same 16 W rows) differ by 64
//   ≡ 0 (mod 8) -> same XCD under round-robin dispatch -> each W row is
//   fetched from HBM once per iteration (round-5 counters confirmed:
//   FETCH ≈ 4 MB = one W read).
//   Per block: 16 j-columns x 5 n-rows. Wave wid owns j = j0+4*wid..+3
//   (4 W rows = 64 VGPRs; VGPR total ~100-110, fits the 128 cap of
//   __launch_bounds__(256,4)). Each qv LDS read now feeds 4 outputs
//   (was 2) and the staged n-tile is 5 rows (20 KiB, was 40) -> LDS-pipe
//   work per output halves vs round 4.
//   Stats: each (ngh, j) partial owned by exactly one wave -> no atomics,
//   no inter-block sync anywhere (rounds 1/5: any device-scope barrier
//   costs ~100 us on this chip).
// ---------------------------------------------------------------------------
__global__ __launch_bounds__(256, 4) void kG(const float* __restrict__ q,
                                             const float* __restrict__ W,
                                             const float* __restrict__ bvec,
                                             float* __restrict__ y,
                                             float* __restrict__ psum,
                                             float* __restrict__ psq) {
    const int tid  = threadIdx.x;
    const int lane = tid & 63;
    const int wid  = tid >> 6;
    const int bid  = blockIdx.x;
    const int ngh  = bid >> 6;         // 0..15
    const int jb   = bid & 63;         // 0..63
    const int n0   = ngh * NROWS;
    const int jw   = jb * 16 + wid * 4;   // this wave's 4 columns

    __shared__ float qs[NROWS][D_DIM];    // 20 KiB

    // W fragment prefetch (in flight during q staging)
    const float4* __restrict__ W4 = (const float4*)W;
    float4 w[4][4];
#pragma unroll
    for (int jj = 0; jj < 4; ++jj)
#pragma unroll
        for (int m = 0; m < 4; ++m)
            w[jj][m] = W4[(size_t)(jw + jj) * 256 + lane + 64 * m];
    const float4 b4 = *(const float4*)(bvec + jw);

    // stage this half-group's q rows into LDS, fully coalesced
    {
        const float4* __restrict__ q4 = (const float4*)(q + (size_t)n0 * D_DIM);
        float4* __restrict__ qs4 = (float4*)qs;
#pragma unroll
        for (int i = 0; i < NROWS; ++i)
            qs4[tid + 256 * i] = q4[tid + 256 * i];
    }
    __syncthreads();

    float csum[4] = {0.f, 0.f, 0.f, 0.f};
    float csq [4] = {0.f, 0.f, 0.f, 0.f};

    for (int nn = 0; nn < NROWS; ++nn) {
        const int n = n0 + nn;
        float4 qv[4];
#pragma unroll
        for (int m = 0; m < 4; ++m)
            qv[m] = ((const float4*)qs[nn])[lane + 64 * m];

        float s[4] = {0.f, 0.f, 0.f, 0.f};
#pragma unroll
        for (int jj = 0; jj < 4; ++jj) {
#pragma unroll
            for (int m = 0; m < 4; ++m) {
                s[jj] += w[jj][m].x * qv[m].x + w[jj][m].y * qv[m].y
                       + w[jj][m].z * qv[m].z + w[jj][m].w * qv[m].w;
            }
        }
#pragma unroll
        for (int off = 32; off; off >>= 1) {
#pragma unroll
            for (int jj = 0; jj < 4; ++jj) s[jj] += __shfl_xor(s[jj], off, 64);
        }
        if (lane == 0) {
            float4 yv = make_float4(s[0] + b4.x, s[1] + b4.y,
                                    s[2] + b4.z, s[3] + b4.w);
            *(float4*)(y + (size_t)n * D_DIM + jw) = yv;
            csum[0] += yv.x; csum[1] += yv.y; csum[2] += yv.z; csum[3] += yv.w;
            csq[0] += yv.x * yv.x; csq[1] += yv.y * yv.y;
            csq[2] += yv.z * yv.z; csq[3] += yv.w * yv.w;
        }
    }
    if (lane == 0) {
        *(float4*)(psum + (size_t)ngh * D_DIM + jw) =
            make_float4(csum[0], csum[1], csum[2], csum[3]);
        *(float4*)(psq  + (size_t)ngh * D_DIM + jw) =
            make_float4(csq[0], csq[1], csq[2], csq[3]);
    }
}

// ---------------------------------------------------------------------------
// kB: reduce NGH=16 partials per column -> BN stats; BN + ReLU + row L2 norm.
// One block per row; one float4 per thread.
// ---------------------------------------------------------------------------
__global__ __launch_bounds__(256) void kB(const float* __restrict__ y,
                                          const float* __restrict__ psum,
                                          const float* __restrict__ psq,
                                          const float* __restrict__ gamma,
                                          const float* __restrict__ beta,
                                          float* __restrict__ out) {
    const int n   = blockIdx.x;
    const int tid = threadIdx.x;

    float4 su = make_float4(0.f, 0.f, 0.f, 0.f);
    float4 sq = make_float4(0.f, 0.f, 0.f, 0.f);
#pragma unroll
    for (int g = 0; g < NGH; ++g) {
        const float4 a = ((const float4*)psum)[g * 256 + tid];
        const float4 b = ((const float4*)psq )[g * 256 + tid];
        su.x += a.x; su.y += a.y; su.z += a.z; su.w += a.w;
        sq.x += b.x; sq.y += b.y; sq.z += b.z; sq.w += b.w;
    }
    const float inv_bs = 1.f / (float)BS;
    const float4 yv = ((const float4*)y)[(size_t)n * 256 + tid];
    const float4 g4 = ((const float4*)gamma)[tid];
    const float4 be = ((const float4*)beta)[tid];

    float4 o;
    {
        const float mu = su.x * inv_bs;
        const float istd = rsqrtf(sq.x * inv_bs - mu * mu + BN_EPS);
        o.x = fmaxf((yv.x - mu) * istd * g4.x + be.x, 0.f);
    }
    {
        const float mu = su.y * inv_bs;
        const float istd = rsqrtf(sq.y * inv_bs - mu * mu + BN_EPS);
        o.y = fmaxf((yv.y - mu) * istd * g4.y + be.y, 0.f);
    }
    {
        const float mu = su.z * inv_bs;
        const float istd = rsqrtf(sq.z * inv_bs - mu * mu + BN_EPS);
        o.z = fmaxf((yv.z - mu) * istd * g4.z + be.z, 0.f);
    }
    {
        const float mu = su.w * inv_bs;
        const float istd = rsqrtf(sq.w * inv_bs - mu * mu + BN_EPS);
        o.w = fmaxf((yv.w - mu) * istd * g4.w + be.w, 0.f);
    }

    float ss = o.x * o.x + o.y * o.y + o.z * o.z + o.w * o.w;
#pragma unroll
    for (int off = 32; off; off >>= 1) ss += __shfl_xor(ss, off, 64);
    __shared__ float sred[4];
    if ((tid & 63) == 0) sred[tid >> 6] = ss;
    __syncthreads();
    const float stot = sred[0] + sred[1] + sred[2] + sred[3];

    const float scale = 1.f / fmaxf(sqrtf(stot), L2_EPS);
    float4 ov = make_float4(o.x * scale, o.y * scale, o.z * scale, o.w * scale);
    ((float4*)out)[(size_t)n * 256 + tid] = ov;
}

extern "C" void kernel_launch(void* const* d_in, const int* in_sizes, int n_in,
                              void* d_out, int out_size, void* d_ws, size_t ws_size,
                              hipStream_t stream) {
    const float* x     = (const float*)d_in[0];
    const float* W     = (const float*)d_in[1];
    const float* bvec  = (const float*)d_in[2];
    const float* gamma = (const float*)d_in[3];
    const float* beta  = (const float*)d_in[4];

    float* q    = (float*)d_ws;          // 80*1024
    float* y    = q + BS * D_DIM;        // 80*1024
    float* psum = y + BS * D_DIM;        // 16*1024
    float* psq  = psum + NGH * D_DIM;    // 16*1024

    float* out = (float*)d_out;

    kQ<<<BS,       256, 0, stream>>>(x, q);
    kG<<<G_BLOCKS, 256, 0, stream>>>(q, W, bvec, y, psum, psq);
    kB<<<BS,       256, 0, stream>>>(y, psum, psq, gamma, beta, out);
}